// Round 7
// baseline (139.046 us; speedup 1.0000x reference)
//
#include <hip/hip_runtime.h>
#include <math.h>

#define N_ATOMS 512
#define MAX_B 128
#define NBUCK 256            // bucket width = 12/256 = 0.046875 (slop halved again)
#define NREP 16              // replicated global histograms
#define WIN 0.35f            // 3.5 sigma; validated round 4 (absmax 0.0078, passed)

// Grid: F * 64 blocks, 256 threads. Block = (frame, 4 bow-tie row-pairs) = 2048 pairs.
// Last block (global ticket) reduces the NREP replica histograms and writes out.
__global__ __launch_bounds__(256) void pair_kernel(
    const float* __restrict__ traj, const float* __restrict__ cell,
    const float* __restrict__ r_list, float* __restrict__ part,
    unsigned int* __restrict__ ticket, float* __restrict__ out,
    int B, int F, int nblocks)
{
    __shared__ float2 qxy[N_ATOMS];
    __shared__ float  qzs[N_ATOMS];
    __shared__ float  dsorted[2048];
    __shared__ int    cnt[NBUCK];
    __shared__ int    start[NBUCK + 1];
    __shared__ int    cursor[NBUCK];
    __shared__ float  accbuf[256];

    const int frame = blockIdx.x >> 6;
    const int sub   = blockIdx.x & 63;
    const int tid   = threadIdx.x;

    const float* q = traj + (size_t)frame * (N_ATOMS * 3);
    for (int a = tid; a < N_ATOMS; a += 256) {
        qxy[a] = make_float2(q[3 * a + 0], q[3 * a + 1]);
        qzs[a] = q[3 * a + 2];
    }
    if (tid < NBUCK) cnt[tid] = 0;
    __syncthreads();

    const float L = cell[0];
    const float invL = 1.0f / L;
    const float cutoff_sq = 0.25f * L * L;
    const float inv_bw = (float)NBUCK / (0.5f * L);   // bucket = d * inv_bw in [0, NBUCK)

    // ---- phase 1a: distances + bucket counts (8 pairs per thread) ----
    float dval[8];
    int   dbuck[8];
    #pragma unroll
    for (int s = 0; s < 8; ++s) {
        const int qidx = s * 256 + tid;            // [0, 2048)
        const int rp   = sub * 4 + (qidx >> 9);    // row-pair [0, 256)
        const int qq   = qidx & 511;
        const int lenA = 511 - rp;                 // row rp: j in (rp, 511]
        const bool inA = qq < lenA;
        const int i = inA ? rp : (510 - rp);       // partner row 510-rp
        const int j = inA ? (rp + 1 + qq) : qq;    // row B: j == qq (exact)
        const bool vp = !(rp == 255 && !inA);      // rp==255 pairs with itself: half only

        const float2 pj = qxy[j];
        const float2 pi = qxy[i];
        float dx = pj.x - pi.x;
        float dy = pj.y - pi.y;
        float dz = qzs[j] - qzs[i];
        dx -= L * floorf(dx * invL + 0.5f);
        dy -= L * floorf(dy * invL + 0.5f);
        dz -= L * floorf(dz * invL + 0.5f);
        const float d2 = dx * dx + dy * dy + dz * dz;

        dbuck[s] = -1;
        dval[s]  = 0.0f;
        if (vp && d2 < cutoff_sq && d2 != 0.0f) {
            const float d = sqrtf(d2);
            int b = (int)(d * inv_bw);
            if (b > NBUCK - 1) b = NBUCK - 1;
            dval[s]  = d;
            dbuck[s] = b;
            atomicAdd(&cnt[b], 1);                 // native ds_add_u32
        }
    }
    __syncthreads();

    // ---- phase 1b: exclusive prefix scan of 256 buckets, one wave, 4/lane ----
    if (tid < 64) {
        const int c0 = cnt[4 * tid + 0];
        const int c1 = cnt[4 * tid + 1];
        const int c2 = cnt[4 * tid + 2];
        const int c3 = cnt[4 * tid + 3];
        const int p  = c0 + c1 + c2 + c3;
        int incl = p;
        #pragma unroll
        for (int off = 1; off < 64; off <<= 1) {
            const int n = __shfl_up(incl, off, 64);
            if (tid >= off) incl += n;
        }
        const int base = incl - p;                 // exclusive start of bucket 4t
        start[4 * tid + 1] = base + c0;
        start[4 * tid + 2] = base + c0 + c1;
        start[4 * tid + 3] = base + c0 + c1 + c2;
        start[4 * tid + 4] = incl;
        cursor[4 * tid + 0] = base;
        cursor[4 * tid + 1] = base + c0;
        cursor[4 * tid + 2] = base + c0 + c1;
        cursor[4 * tid + 3] = base + c0 + c1 + c2;
        if (tid == 0) start[0] = 0;
    }
    __syncthreads();

    // ---- phase 1c: scatter distances into bucket-sorted order ----
    #pragma unroll
    for (int s = 0; s < 8; ++s) {
        if (dbuck[s] >= 0) {
            const int pos = atomicAdd(&cursor[dbuck[s]], 1);
            dsorted[pos] = dval[s];
        }
    }
    __syncthreads();

    // ---- phase 2: bin-centric accumulation, bin-per-lane, block-rotated ----
    const int rot = (sub & 3) << 5;
    const int k = (tid + rot) & 127;
    const int g = tid >> 7;
    float acc = 0.0f;
    if (k < B) {
        const float rk = r_list[k];
        const float c1 = -50.0f;
        const float c2 = 100.0f * rk;
        const float c3 = -50.0f * rk * rk;
        int blo = (int)(fmaxf((rk - WIN) * inv_bw, 0.0f));
        int bhi = (int)((rk + WIN) * inv_bw);
        if (bhi > NBUCK - 1) bhi = NBUCK - 1;
        const int lo = start[blo];
        const int hi = start[bhi + 1];
        int idx = lo + g;
        int nn = hi - idx;
        nn = (nn > 0) ? ((nn + 1) >> 1) : 0;       // elems for this lane at stride 2
        float acc1 = 0.0f;
        int m = nn >> 1;
        while (m-- > 0) {                          // 2-deep: both ds_reads in flight
            const float d0 = dsorted[idx];
            const float d1 = dsorted[idx + 2];
            idx += 4;
            acc  += __expf(fmaf(d0, fmaf(c1, d0, c2), c3));
            acc1 += __expf(fmaf(d1, fmaf(c1, d1, c2), c3));
        }
        if (nn & 1) {
            const float d0 = dsorted[idx];
            acc += __expf(fmaf(d0, fmaf(c1, d0, c2), c3));
        }
        acc += acc1;
    }
    accbuf[tid] = acc;
    __syncthreads();

    // ---- flush: device-scope atomic add into replica (blockIdx & 15) ----
    if (tid < 128) {
        const int kb = (tid + rot) & 127;
        const float v = accbuf[tid] + accbuf[tid + 128];
        atomicAdd(&part[(blockIdx.x & (NREP - 1)) * MAX_B + kb], v);
    }
    __threadfence();                               // adds visible before ticket
    __syncthreads();

    // ---- last-block finalize ----
    __shared__ unsigned int myticket;
    if (tid == 0)
        myticket = __hip_atomic_fetch_add(ticket, 1u, __ATOMIC_ACQ_REL,
                                          __HIP_MEMORY_SCOPE_AGENT);
    __syncthreads();
    if (myticket != (unsigned int)(nblocks - 1)) return;

    if (tid < MAX_B && tid < B) {
        float s = 0.0f;
        #pragma unroll
        for (int ch = 0; ch < NREP; ++ch)
            s += __hip_atomic_load(&part[ch * MAX_B + tid], __ATOMIC_RELAXED,
                                   __HIP_MEMORY_SCOPE_AGENT);
        const float r = r_list[tid];
        out[tid] = r;                                  // output 0: r_list
        const float det = cell[0] * cell[4] * cell[8];
        const float rp = r + 0.05f;
        const float rm = r - 0.05f;
        const float v = (4.0f * (float)M_PI / 3.0f) * (rp * rp * rp - rm * rm * rm);
        const float inv_sqrt2pi = 0.3989422804014327f;
        const float h = s * inv_sqrt2pi / (float)F;
        const float gr = h / v * det / (float)(N_ATOMS - 1) / (float)N_ATOMS * 2.0f;
        out[B + tid] = gr;                             // output 1: gr
    }
}

extern "C" void kernel_launch(void* const* d_in, const int* in_sizes, int n_in,
                              void* d_out, int out_size, void* d_ws, size_t ws_size,
                              hipStream_t stream) {
    const float* traj   = (const float*)d_in[0];
    const float* cell   = (const float*)d_in[1];
    const float* r_list = (const float*)d_in[2];
    float* out  = (float*)d_out;
    float* part = (float*)d_ws;
    unsigned int* ticket = (unsigned int*)(part + NREP * MAX_B);

    const int B = in_sizes[2];
    const int F = in_sizes[0] / (N_ATOMS * 3);
    const int nblocks = F * 64;

    // zero NREP replica histograms + ticket counter (8 KB + 4 B), then one
    // fused kernel: pair accumulation + last-block finalize.
    hipMemsetAsync(part, 0, (size_t)(NREP * MAX_B) * sizeof(float) + sizeof(unsigned int),
                   stream);
    hipLaunchKernelGGL(pair_kernel, dim3(nblocks), dim3(256), 0, stream,
                       traj, cell, r_list, part, ticket, out, B, F, nblocks);
}

// Round 8
// 68.172 us; speedup vs baseline: 2.0396x; 2.0396x over previous
//
#include <hip/hip_runtime.h>
#include <math.h>

#define N_ATOMS 512
#define MAX_B 128
#define NBUCK 256            // bucket width = 12/256 = 0.046875; scan = 1 wave, 4/lane
#define WIN 0.35f            // 3.5 sigma; validated r4/r7 (absmax 0.0078, passes)

__global__ void zero_kernel(float* p, int n) {
    int t = blockIdx.x * blockDim.x + threadIdx.x;
    if (t < n) p[t] = 0.0f;
}

// Grid: F * 64 blocks, 256 threads. Block = (frame, 4 bow-tie row-pairs) = 2048 pairs.
__global__ __launch_bounds__(256) void pair_kernel(
    const float* __restrict__ traj, const float* __restrict__ cell,
    const float* __restrict__ r_list, float* __restrict__ part,
    int B, int atomic_mode)
{
    __shared__ float2 qxy[N_ATOMS];
    __shared__ float  qzs[N_ATOMS];
    __shared__ float  dsorted[2048];
    __shared__ int    cnt[NBUCK];
    __shared__ int    start[NBUCK + 1];
    __shared__ int    cursor[NBUCK];
    __shared__ float  accbuf[256];

    const int frame = blockIdx.x >> 6;
    const int sub   = blockIdx.x & 63;
    const int tid   = threadIdx.x;

    const float* q = traj + (size_t)frame * (N_ATOMS * 3);
    for (int a = tid; a < N_ATOMS; a += 256) {
        qxy[a] = make_float2(q[3 * a + 0], q[3 * a + 1]);
        qzs[a] = q[3 * a + 2];
    }
    if (tid < NBUCK) cnt[tid] = 0;
    __syncthreads();

    const float L = cell[0];
    const float invL = 1.0f / L;
    const float cutoff_sq = 0.25f * L * L;
    const float inv_bw = (float)NBUCK / (0.5f * L);   // bucket = d * inv_bw in [0, NBUCK)

    // ---- phase 1a: distances + bucket counts (8 pairs per thread) ----
    float dval[8];
    int   dbuck[8];
    #pragma unroll
    for (int s = 0; s < 8; ++s) {
        const int qidx = s * 256 + tid;            // [0, 2048)
        const int rp   = sub * 4 + (qidx >> 9);    // row-pair [0, 256)
        const int qq   = qidx & 511;
        const int lenA = 511 - rp;                 // row rp: j in (rp, 511]
        const bool inA = qq < lenA;
        const int i = inA ? rp : (510 - rp);       // partner row 510-rp
        const int j = inA ? (rp + 1 + qq) : qq;    // row B: j == qq (exact)
        const bool vp = !(rp == 255 && !inA);      // rp==255 pairs with itself: half only

        const float2 pj = qxy[j];
        const float2 pi = qxy[i];
        float dx = pj.x - pi.x;
        float dy = pj.y - pi.y;
        float dz = qzs[j] - qzs[i];
        dx -= L * floorf(dx * invL + 0.5f);
        dy -= L * floorf(dy * invL + 0.5f);
        dz -= L * floorf(dz * invL + 0.5f);
        const float d2 = dx * dx + dy * dy + dz * dz;

        dbuck[s] = -1;
        dval[s]  = 0.0f;
        if (vp && d2 < cutoff_sq && d2 != 0.0f) {
            const float d = sqrtf(d2);
            int b = (int)(d * inv_bw);
            if (b > NBUCK - 1) b = NBUCK - 1;
            dval[s]  = d;
            dbuck[s] = b;
            atomicAdd(&cnt[b], 1);                 // native ds_add_u32
        }
    }
    __syncthreads();

    // ---- phase 1b: exclusive prefix scan of 256 buckets, one wave, 4/lane ----
    if (tid < 64) {
        const int c0 = cnt[4 * tid + 0];
        const int c1 = cnt[4 * tid + 1];
        const int c2 = cnt[4 * tid + 2];
        const int c3 = cnt[4 * tid + 3];
        const int p  = c0 + c1 + c2 + c3;
        int incl = p;
        #pragma unroll
        for (int off = 1; off < 64; off <<= 1) {
            const int n = __shfl_up(incl, off, 64);
            if (tid >= off) incl += n;
        }
        const int base = incl - p;                 // exclusive start of bucket 4t
        start[4 * tid + 1] = base + c0;
        start[4 * tid + 2] = base + c0 + c1;
        start[4 * tid + 3] = base + c0 + c1 + c2;
        start[4 * tid + 4] = incl;
        cursor[4 * tid + 0] = base;
        cursor[4 * tid + 1] = base + c0;
        cursor[4 * tid + 2] = base + c0 + c1;
        cursor[4 * tid + 3] = base + c0 + c1 + c2;
        if (tid == 0) start[0] = 0;
    }
    __syncthreads();

    // ---- phase 1c: scatter distances into bucket-sorted order ----
    #pragma unroll
    for (int s = 0; s < 8; ++s) {
        if (dbuck[s] >= 0) {
            const int pos = atomicAdd(&cursor[dbuck[s]], 1);
            dsorted[pos] = dval[s];
        }
    }
    __syncthreads();

    // ---- phase 2: bin-centric accumulation, bin-per-lane, block-rotated ----
    // Rotation spreads the heavy (high-r) bins across different waves for
    // different blocks, evening per-SIMD straggler load. Bijective on [0,128).
    const int rot = (sub & 3) << 5;
    const int k = (tid + rot) & 127;
    const int g = tid >> 7;
    float acc = 0.0f;
    if (k < B) {
        const float rk = r_list[k];
        const float c1 = -50.0f;
        const float c2 = 100.0f * rk;
        const float c3 = -50.0f * rk * rk;
        int blo = (int)(fmaxf((rk - WIN) * inv_bw, 0.0f));
        int bhi = (int)((rk + WIN) * inv_bw);
        if (bhi > NBUCK - 1) bhi = NBUCK - 1;
        const int lo = start[blo];
        const int hi = start[bhi + 1];
        int idx = lo + g;
        int nn = hi - idx;
        nn = (nn > 0) ? ((nn + 1) >> 1) : 0;       // elems for this lane at stride 2
        float acc1 = 0.0f;
        int m = nn >> 1;
        while (m-- > 0) {                          // 2-deep: both ds_reads in flight
            const float d0 = dsorted[idx];
            const float d1 = dsorted[idx + 2];
            idx += 4;
            acc  += __expf(fmaf(d0, fmaf(c1, d0, c2), c3));
            acc1 += __expf(fmaf(d1, fmaf(c1, d1, c2), c3));
        }
        if (nn & 1) {
            const float d0 = dsorted[idx];
            acc += __expf(fmaf(d0, fmaf(c1, d0, c2), c3));
        }
        acc += acc1;
    }
    accbuf[tid] = acc;
    __syncthreads();

    if (tid < 128) {
        // threads tid and tid+128 map to the same bin k (g=0/1)
        const int kb = (tid + rot) & 127;
        const float v = accbuf[tid] + accbuf[tid + 128];
        if (atomic_mode) atomicAdd(&part[(blockIdx.x & 15) * MAX_B + kb], v);
        else             part[(size_t)blockIdx.x * MAX_B + kb] = v;
    }
}

// Grid: 128 blocks; block k reduces bin k over nrows partial histograms.
__global__ __launch_bounds__(256) void finalize_kernel(
    const float* __restrict__ r_list, const float* __restrict__ cell,
    const float* __restrict__ part, float* __restrict__ out,
    int B, int F, int nrows)
{
    __shared__ float red[256];
    const int k = blockIdx.x;
    if (k >= B) return;

    float s = 0.0f;
    for (int t = threadIdx.x; t < nrows; t += 256) s += part[(size_t)t * MAX_B + k];
    red[threadIdx.x] = s;
    __syncthreads();
    for (int off = 128; off > 0; off >>= 1) {
        if (threadIdx.x < off) red[threadIdx.x] += red[threadIdx.x + off];
        __syncthreads();
    }
    if (threadIdx.x == 0) {
        const float r = r_list[k];
        out[k] = r;                                    // output 0: r_list
        const float det = cell[0] * cell[4] * cell[8];
        const float rp = r + 0.05f;
        const float rm = r - 0.05f;
        const float v = (4.0f * (float)M_PI / 3.0f) * (rp * rp * rp - rm * rm * rm);
        const float inv_sqrt2pi = 0.3989422804014327f;
        const float h = red[0] * inv_sqrt2pi / (float)F;
        const float gr = h / v * det / (float)(N_ATOMS - 1) / (float)N_ATOMS * 2.0f;
        out[B + k] = gr;                               // output 1: gr
    }
}

extern "C" void kernel_launch(void* const* d_in, const int* in_sizes, int n_in,
                              void* d_out, int out_size, void* d_ws, size_t ws_size,
                              hipStream_t stream) {
    const float* traj   = (const float*)d_in[0];
    const float* cell   = (const float*)d_in[1];
    const float* r_list = (const float*)d_in[2];
    float* out  = (float*)d_out;
    float* part = (float*)d_ws;

    const int B = in_sizes[2];
    const int F = in_sizes[0] / (N_ATOMS * 3);
    const int nblocks = F * 64;

    const bool partials_fit =
        ws_size >= (size_t)nblocks * MAX_B * sizeof(float);

    if (partials_fit) {
        // 2 dispatches: unique-slot partials (no init needed), then reduce.
        hipLaunchKernelGGL(pair_kernel, dim3(nblocks), dim3(256), 0, stream,
                           traj, cell, r_list, part, B, 0);
        hipLaunchKernelGGL(finalize_kernel, dim3(MAX_B), dim3(256), 0, stream,
                           r_list, cell, part, out, B, F, nblocks);
    } else {
        // Fallback: 16 replicated atomic histograms (8 KB), needs zeroing.
        hipLaunchKernelGGL(zero_kernel, dim3(8), dim3(256), 0, stream,
                           part, 16 * MAX_B);
        hipLaunchKernelGGL(pair_kernel, dim3(nblocks), dim3(256), 0, stream,
                           traj, cell, r_list, part, B, 1);
        hipLaunchKernelGGL(finalize_kernel, dim3(MAX_B), dim3(256), 0, stream,
                           r_list, cell, part, out, B, F, 16);
    }
}